// Round 8
// baseline (188.581 us; speedup 1.0000x reference)
//
#include <hip/hip_runtime.h>
#include <hip/hip_bf16.h>

// VectorQuantizer on MI355X — Round 15: resubmit R14 (container infra
// failure, kernel never executed; source audited — no OOB/deadlock).
// z: [32, 64, 64, 64] fp32 (B,C,H,W), emb: [1024, 64] fp32.
// out: z_q [32,64,64,64] fp32 (8388608) then loss (1 float).
//
// R13 post-mortem: fin-fusion neutral -> gaps aren't the lever. Budget:
// fills ~48 (harness-fixed) + prep ~3 + vq ~40 + overhead ~17. vq is
// latency-bound (Mfma 12 / VALU 29 / Occ 37%): 1024-thread blocks cap
// at 2 blocks/CU (2048-thread limit) and each is a 16-wave barrier
// convoy — nothing hides the stage-phase HBM latency. vq floor ~15-20.
// R14/R15: 512 threads (8 waves), 128 px/block, 1024 blocks -> 4
// blocks/CU (LDS 37.3KB x4 = 149 < 160; threads 4x512 = 2048). Codes
// in TWO passes (g = ps*32 + wv*4 + kt): per-wave live set identical
// to the proven 48-VGPR kernel -> launch_bounds(512,8) (<=64 VGPR)
// should bind. afr reloaded from L2-resident fragws between passes.
// kbuf: 32 entries/px (8 waves x 2 passes x 2 halves), stride 40w;
// epilogue = R11 verbatim. Diagnostics: VGPR<=64, Occupancy -> 60-75%.

#define NELEM 8388608
#define NBLK  1024

typedef short sv8 __attribute__((ext_vector_type(8)));
typedef float fv4 __attribute__((ext_vector_type(4)));
typedef int   iv4 __attribute__((ext_vector_type(4)));
typedef unsigned int uint32;
typedef uint32 uv4 __attribute__((ext_vector_type(4)));

__device__ __forceinline__ uint32 pack2bf(float a, float b) {
    __hip_bfloat162 h = __float22bfloat162_rn(make_float2(a, b));
    union { __hip_bfloat162 h2; uint32 u; } cvt;
    cvt.h2 = h;
    return cvt.u;             // low 16 = a, high 16 = b
}

__device__ __forceinline__ uint32 umax(uint32 a, uint32 b) { return a > b ? a : b; }

// ---- prep: codebook -> bf16 A-frags (fragment order) + e2n = 1-0.5||e||^2.
//      Also zeroes the loss slot (stream-ordered before vq every replay).
__global__ __launch_bounds__(256) void prep_kernel(
        const float* __restrict__ embf,
        iv4* __restrict__ fragws,            // 8192 units of 16B
        float* __restrict__ e2n,             // 1024 floats
        float* __restrict__ out_loss) {
    if (blockIdx.x == 0 && threadIdx.x == 0) out_loss[0] = 0.0f;
    const int t = blockIdx.x * 256 + threadIdx.x;   // 0..4095
    const int g = t >> 6, l = t & 63;
    const int code = g * 16 + (l & 15);
    const int q    = l >> 4;
    float s2 = 0.0f;
#pragma unroll
    for (int kc = 0; kc < 2; ++kc) {
        fv4 u0 = ((const fv4*)embf)[code * 16 + kc * 8 + q * 2 + 0];
        fv4 u1 = ((const fv4*)embf)[code * 16 + kc * 8 + q * 2 + 1];
        s2 += u0[0]*u0[0] + u0[1]*u0[1] + u0[2]*u0[2] + u0[3]*u0[3]
            + u1[0]*u1[0] + u1[1]*u1[1] + u1[2]*u1[2] + u1[3]*u1[3];
        iv4 pv = { (int)pack2bf(u0[0], u0[1]), (int)pack2bf(u0[2], u0[3]),
                   (int)pack2bf(u1[0], u1[1]), (int)pack2bf(u1[2], u1[3]) };
        fragws[(g * 2 + kc) * 64 + l] = pv;
    }
    s2 += __shfl_xor(s2, 16);
    s2 += __shfl_xor(s2, 32);                // full ||e_code||^2
    if (q == 0) e2n[code] = 1.0f - 0.5f * s2;
}

__global__ __launch_bounds__(512, 8) void vq_kernel(
        const float* __restrict__ z,
        const float* __restrict__ embf,
        const iv4* __restrict__ fragws,
        const float* __restrict__ e2n,
        float* __restrict__ out) {
    __shared__ iv4    zfrag[16 * 64];        // 16 KB  B-frags [pt*2+kc][lane]
    __shared__ uv4    kbuf4[128 * 10];       // 20 KB  keys [pixel][32 entries]
    __shared__ float  zn2[128 * 2];          //  1 KB  ||z||^2 halves per pixel
    __shared__ float  lred[8];

    uint32* kbuf = (uint32*)kbuf4;

    const int tid   = threadIdx.x;
    const int blk   = blockIdx.x;
    const int batch = blk >> 5;
    const int hw0   = (blk & 31) << 7;       // 128 pixels in the 64x64 plane
    const int zb    = batch * 262144;        // + c*4096 + (hw0 + p)

    const int wv   = tid >> 6;               // 0..7
    const int lane = tid & 63;
    const int q    = lane >> 4;
    const int mcol = lane & 15;

    // ---- stage z -> bf16 B-frags + fp32 ||z||^2 partials
#pragma unroll
    for (int m = 0; m < 2; ++m) {
        const int R   = m * 8 + wv;          // pt*2 + kc, 0..15
        const int col = hw0 + (R >> 1) * 16 + mcol;
        const int cb  = (R & 1) * 32 + q * 8;
        uint32 pk[4];
        float  sq = 0.0f;
#pragma unroll
        for (int jj = 0; jj < 4; ++jj) {
            float f0 = z[zb + (cb + jj * 2 + 0) * 4096 + col];
            float f1 = z[zb + (cb + jj * 2 + 1) * 4096 + col];
            sq += f0 * f0 + f1 * f1;
            pk[jj] = pack2bf(f0, f1);
        }
        iv4 v = { (int)pk[0], (int)pk[1], (int)pk[2], (int)pk[3] };
        zfrag[R * 64 + lane] = v;            // lane-contiguous: conflict-free
        sq += __shfl_xor(sq, 16);
        sq += __shfl_xor(sq, 32);
        if (q == 0) zn2[((R >> 1) * 16 + mcol) * 2 + (R & 1)] = sq;
    }
    __syncthreads();

    // ---- two passes over the codebook: pass ps covers codes
    // [ps*512, ps*512+512); wave wv owns groups g = ps*32 + wv*4 + kt.
#pragma unroll
    for (int ps = 0; ps < 2; ++ps) {
        sv8    afr[4][2];
        fv4    einit[4];
        uint32 inv[4][4];
#pragma unroll
        for (int kt = 0; kt < 4; ++kt) {
            const int g = ps * 32 + wv * 4 + kt;
#pragma unroll
            for (int kc = 0; kc < 2; ++kc) {
                iv4 pv = fragws[(g * 2 + kc) * 64 + lane];
                afr[kt][kc] = *(sv8*)&pv;
            }
            einit[kt] = *(const fv4*)(e2n + g * 16 + q * 4);
#pragma unroll
            for (int r = 0; r < 4; ++r)
                inv[kt][r] = (uint32)(1023 - (g * 16 + q * 4 + r));
        }

        // ---- main loop: 8 pixel-tiles, branchless key-max, ONE shfl
#pragma unroll 2
        for (int pt = 0; pt < 8; ++pt) {
            sv8 b0 = ((const sv8*)zfrag)[(pt * 2 + 0) * 64 + lane];
            sv8 b1 = ((const sv8*)zfrag)[(pt * 2 + 1) * 64 + lane];
            uint32 kk[4];
#pragma unroll
            for (int kt = 0; kt < 4; ++kt) {
                fv4 acc = einit[kt];
                acc = __builtin_amdgcn_mfma_f32_16x16x32_bf16(afr[kt][0], b0, acc, 0, 0, 0);
                acc = __builtin_amdgcn_mfma_f32_16x16x32_bf16(afr[kt][1], b1, acc, 0, 0, 0);
                uint32 k0 = (__float_as_uint(acc[0]) & 0xFFFFFC00u) | inv[kt][0];
                uint32 k1 = (__float_as_uint(acc[1]) & 0xFFFFFC00u) | inv[kt][1];
                uint32 k2 = (__float_as_uint(acc[2]) & 0xFFFFFC00u) | inv[kt][2];
                uint32 k3 = (__float_as_uint(acc[3]) & 0xFFFFFC00u) | inv[kt][3];
                kk[kt] = umax(umax(k0, k1), umax(k2, k3));
            }
            uint32 key = umax(umax(kk[0], kk[1]), umax(kk[2], kk[3]));
            key = umax(key, (uint32)__shfl_xor((int)key, 16));
            // lanes q=0 hold max(q0,q1); q=2 hold max(q2,q3)
            if ((q & 1) == 0)
                kbuf[(pt * 16 + mcol) * 40 + ps * 16 + wv * 2 + (q >> 1)] = key;
        }
    }
    __syncthreads();

    // ---- per-wave epilogue: wave wv owns pixels [wv*16, wv*16+16).
    // 4 lanes per pixel: lane = 4*dp + e; two b128 reads cover entries
    // [e*8, e*8+8) of the 32-entry kbuf row (stride 40w -> 16B aligned).
    {
        const int dp = lane >> 2;            // 0..15  pixel within wave
        const int e  = lane & 3;             // entry octet
        const int p  = wv * 16 + dp;         // pixel in block, 0..127

        uv4 ka = kbuf4[p * 10 + e * 2 + 0];
        uv4 kb = kbuf4[p * 10 + e * 2 + 1];
        uint32 best = umax(umax(umax(ka[0], ka[1]), umax(ka[2], ka[3])),
                           umax(umax(kb[0], kb[1]), umax(kb[2], kb[3])));
        best = umax(best, (uint32)__shfl_xor((int)best, 1));
        best = umax(best, (uint32)__shfl_xor((int)best, 2));
        const int id = 1023 - (int)(best & 1023u);

        // loss (lane e==0 of each pixel group), then wave-sum over e==0 lanes
        float myloss = 0.0f;
        if (e == 0) {
            const float sc = __uint_as_float(best & 0xFFFFFC00u);
            myloss = zn2[p * 2] + zn2[p * 2 + 1] - 2.0f * (sc - 1.0f);
        }
#pragma unroll
        for (int off = 4; off < 64; off <<= 1) myloss += __shfl_down(myloss, off);
        if (lane == 0) lred[wv] = myloss;

        // gather: 4 lanes per code row (16 lines/load), 64B per lane
        // stores: fixed (jj,ee): 16 consecutive p x 4 c = 4x64B segments
#pragma unroll
        for (int jj = 0; jj < 4; ++jj) {
            fv4 ev = ((const fv4*)embf)[id * 16 + e * 4 + jj];
#pragma unroll
            for (int ee = 0; ee < 4; ++ee) {
                const int c = e * 16 + jj * 4 + ee;
                out[zb + c * 4096 + hw0 + p] = ev[ee];  // z + (z_q - z) == z_q
            }
        }
    }
    __syncthreads();

    // ---- fused finalization: one pre-scaled device atomic per block.
    if (tid == 0) {
        float s = 0.0f;
#pragma unroll
        for (int i = 0; i < 8; ++i) s += lred[i];
        atomicAdd(out + NELEM, s * (1.5f / (float)NELEM));
    }
}

extern "C" void kernel_launch(void* const* d_in, const int* in_sizes, int n_in,
                              void* d_out, int out_size, void* d_ws, size_t ws_size,
                              hipStream_t stream) {
    const float* z    = (const float*)d_in[0];
    const float* embf = (const float*)d_in[1];
    float* out        = (float*)d_out;

    iv4*   fragws = (iv4*)d_ws;                            // 128 KB
    float* e2n    = (float*)((char*)d_ws + 131072);        // 4 KB

    prep_kernel<<<dim3(16), dim3(256), 0, stream>>>(embf, fragws, e2n, out + NELEM);
    vq_kernel<<<dim3(NBLK), dim3(512), 0, stream>>>(z, embf, fragws, e2n, out);
}

// Round 9
// 104.832 us; speedup vs baseline: 1.7989x; 1.7989x over previous
//
#include <hip/hip_runtime.h>
#include <hip/hip_bf16.h>

// VectorQuantizer on MI355X — Round 16: barrier-free main loop
// (codebook in LDS, pixels in registers).
// z: [32, 64, 64, 64] fp32 (B,C,H,W), emb: [1024, 64] fp32.
// out: z_q [32,64,64,64] fp32 (8388608) then loss (1 float).
//
// R15 post-mortem: (512,8) forced 64-reg budget -> scratch spills
// (FETCH 194MB/WRITE 137MB = spill traffic), vq 120 us. R13 data:
// 48 VGPR + AGPRs -> only 1 block/CU resident (Occ 37%) -> the two
// full-block barriers serialize stage/compute/epilogue phases: 40 us
// ~= no-overlap pipe sum. Can't fit 2 blocks; so remove the barriers
// instead. R16: wave owns 32 px with B-frags IN REGISTERS (no zfrag,
// no kbuf, no mid barriers); codebook A-frags (128 KB) + e2n (4 KB)
// staged to LDS once; 64-g loop {3 ds_read + 4 MFMA + 8 and_or/umax}
// is per-wave independent — waves drift, latency self-hides at
// 1 block/CU. Argmax = per-lane running packed-key max + 2 shfls at
// the end. All component math verbatim from proven R11/R13. 256
// blocks x 1024 thr. Tells: WRITE ~33 MB (no spill), conflicts ~0.

#define NELEM 8388608
#define NBLK  256

typedef short sv8 __attribute__((ext_vector_type(8)));
typedef float fv4 __attribute__((ext_vector_type(4)));
typedef int   iv4 __attribute__((ext_vector_type(4)));
typedef unsigned int uint32;

__device__ __forceinline__ uint32 pack2bf(float a, float b) {
    __hip_bfloat162 h = __float22bfloat162_rn(make_float2(a, b));
    union { __hip_bfloat162 h2; uint32 u; } cvt;
    cvt.h2 = h;
    return cvt.u;             // low 16 = a, high 16 = b
}

__device__ __forceinline__ uint32 umax(uint32 a, uint32 b) { return a > b ? a : b; }

// ---- prep: codebook -> bf16 A-frags (fragment order) + e2n = 1-0.5||e||^2.
//      Also zeroes the loss slot (stream-ordered before vq every replay).
__global__ __launch_bounds__(256) void prep_kernel(
        const float* __restrict__ embf,
        iv4* __restrict__ fragws,            // 8192 units of 16B
        float* __restrict__ e2n,             // 1024 floats
        float* __restrict__ out_loss) {
    if (blockIdx.x == 0 && threadIdx.x == 0) out_loss[0] = 0.0f;
    const int t = blockIdx.x * 256 + threadIdx.x;   // 0..4095
    const int g = t >> 6, l = t & 63;
    const int code = g * 16 + (l & 15);
    const int q    = l >> 4;
    float s2 = 0.0f;
#pragma unroll
    for (int kc = 0; kc < 2; ++kc) {
        fv4 u0 = ((const fv4*)embf)[code * 16 + kc * 8 + q * 2 + 0];
        fv4 u1 = ((const fv4*)embf)[code * 16 + kc * 8 + q * 2 + 1];
        s2 += u0[0]*u0[0] + u0[1]*u0[1] + u0[2]*u0[2] + u0[3]*u0[3]
            + u1[0]*u1[0] + u1[1]*u1[1] + u1[2]*u1[2] + u1[3]*u1[3];
        iv4 pv = { (int)pack2bf(u0[0], u0[1]), (int)pack2bf(u0[2], u0[3]),
                   (int)pack2bf(u1[0], u1[1]), (int)pack2bf(u1[2], u1[3]) };
        fragws[(g * 2 + kc) * 64 + l] = pv;
    }
    s2 += __shfl_xor(s2, 16);
    s2 += __shfl_xor(s2, 32);                // full ||e_code||^2
    if (q == 0) e2n[code] = 1.0f - 0.5f * s2;
}

__global__ __launch_bounds__(1024, 4) void vq_kernel(
        const float* __restrict__ z,
        const float* __restrict__ embf,
        const iv4* __restrict__ fragws,
        const float* __restrict__ e2n,
        float* __restrict__ out) {
    __shared__ iv4   afr_lds[128 * 64];      // 128 KB  A-frags [g*2+kc][lane]
    __shared__ float e2nl[1024];             //   4 KB  1-0.5||e||^2
    __shared__ float lred[16];

    const int tid   = threadIdx.x;
    const int blk   = blockIdx.x;
    const int batch = blk >> 3;
    const int hw0   = (blk & 7) << 9;        // 512 pixels per block
    const int zb    = batch * 262144;        // + c*4096 + px

    const int wv   = tid >> 6;               // 0..15
    const int lane = tid & 63;
    const int q    = lane >> 4;
    const int mcol = lane & 15;
    const int pxb  = hw0 + wv * 32;          // wave's 32 pixels

    // ---- own B-frags (2 px-groups of 16) in registers + ||z||^2.
    // Issue HBM z-loads first; codebook LDS-stage overlaps their latency.
    sv8   bfr[2][2];
    float zn[2];
#pragma unroll
    for (int j = 0; j < 2; ++j) {
        const int col = pxb + j * 16 + mcol;
        float sq = 0.0f;
#pragma unroll
        for (int kc = 0; kc < 2; ++kc) {
            uint32 pk[4];
#pragma unroll
            for (int jj = 0; jj < 4; ++jj) {
                float f0 = z[zb + (kc * 32 + q * 8 + jj * 2 + 0) * 4096 + col];
                float f1 = z[zb + (kc * 32 + q * 8 + jj * 2 + 1) * 4096 + col];
                sq += f0 * f0 + f1 * f1;
                pk[jj] = pack2bf(f0, f1);
            }
            iv4 v = { (int)pk[0], (int)pk[1], (int)pk[2], (int)pk[3] };
            bfr[j][kc] = *(sv8*)&v;
        }
        sq += __shfl_xor(sq, 16);
        sq += __shfl_xor(sq, 32);            // full ||z_px||^2
        zn[j] = sq;
    }

    // ---- stage codebook frags + e2n to LDS (L2-hot, coalesced)
#pragma unroll
    for (int i = 0; i < 8; ++i)
        afr_lds[i * 1024 + tid] = fragws[i * 1024 + tid];
    e2nl[tid] = e2n[tid];
    __syncthreads();

    // ---- main loop: 64 code-groups, BARRIER-FREE, per-wave independent
    uint32 best0 = 0u, best1 = 0u;
    const uint32 mask = 0xFFFFFC00u;
#pragma unroll 2
    for (int g = 0; g < 64; ++g) {
        iv4 pa0 = afr_lds[(g * 2 + 0) * 64 + lane];
        iv4 pa1 = afr_lds[(g * 2 + 1) * 64 + lane];
        sv8 a0 = *(sv8*)&pa0;
        sv8 a1 = *(sv8*)&pa1;
        fv4 einit = *(const fv4*)(e2nl + g * 16 + q * 4);
        const uint32 invb = (uint32)(1023 - (g * 16 + q * 4));
        fv4 acc0 = __builtin_amdgcn_mfma_f32_16x16x32_bf16(a0, bfr[0][0], einit, 0, 0, 0);
        acc0     = __builtin_amdgcn_mfma_f32_16x16x32_bf16(a1, bfr[0][1], acc0,  0, 0, 0);
        fv4 acc1 = __builtin_amdgcn_mfma_f32_16x16x32_bf16(a0, bfr[1][0], einit, 0, 0, 0);
        acc1     = __builtin_amdgcn_mfma_f32_16x16x32_bf16(a1, bfr[1][1], acc1,  0, 0, 0);
#pragma unroll
        for (int r = 0; r < 4; ++r) {
            best0 = umax(best0, (__float_as_uint(acc0[r]) & mask) | (invb - (uint32)r));
            best1 = umax(best1, (__float_as_uint(acc1[r]) & mask) | (invb - (uint32)r));
        }
    }

    // ---- epilogue: finish argmax with 2 shfls, loss, gather, store
    float myloss = 0.0f;
#pragma unroll
    for (int j = 0; j < 2; ++j) {
        uint32 b = j ? best1 : best0;
        b = umax(b, (uint32)__shfl_xor((int)b, 16));
        b = umax(b, (uint32)__shfl_xor((int)b, 32));   // all 4 q-lanes have it
        const int id = 1023 - (int)(b & 1023u);
        if (q == 0) {
            const float sc = __uint_as_float(b & mask);
            myloss += zn[j] - 2.0f * (sc - 1.0f);
        }
        const int col = pxb + j * 16 + mcol;
        // gather: 4 q-lanes each fetch a quarter of the emb row (64 B)
#pragma unroll
        for (int jjj = 0; jjj < 4; ++jjj) {
            fv4 ev = ((const fv4*)embf)[id * 16 + q * 4 + jjj];
#pragma unroll
            for (int ee = 0; ee < 4; ++ee) {
                const int c = q * 16 + jjj * 4 + ee;
                out[zb + c * 4096 + col] = ev[ee];  // z + (z_q - z) == z_q
            }
        }
    }

    // ---- loss: wave butterfly (only q==0 lanes nonzero), then atomic
#pragma unroll
    for (int off = 1; off < 64; off <<= 1)
        myloss += __shfl_xor(myloss, off);
    if (lane == 0) lred[wv] = myloss;
    __syncthreads();
    if (tid == 0) {
        float s = 0.0f;
#pragma unroll
        for (int i = 0; i < 16; ++i) s += lred[i];
        atomicAdd(out + NELEM, s * (1.5f / (float)NELEM));
    }
}

extern "C" void kernel_launch(void* const* d_in, const int* in_sizes, int n_in,
                              void* d_out, int out_size, void* d_ws, size_t ws_size,
                              hipStream_t stream) {
    const float* z    = (const float*)d_in[0];
    const float* embf = (const float*)d_in[1];
    float* out        = (float*)d_out;

    iv4*   fragws = (iv4*)d_ws;                            // 128 KB
    float* e2n    = (float*)((char*)d_ws + 131072);        // 4 KB

    prep_kernel<<<dim3(16), dim3(256), 0, stream>>>(embf, fragws, e2n, out + NELEM);
    vq_kernel<<<dim3(NBLK), dim3(1024), 0, stream>>>(z, embf, fragws, e2n, out);
}